// Round 13
// baseline (550.055 us; speedup 1.0000x reference)
//
#include <hip/hip_runtime.h>
#include <hip/hip_fp16.h>
#include <math.h>

#define B_ 16
#define L_ 2048
#define D_ 256
#define N_ 64
#define NBLK_ 6
#define LC_ 128
#define NC_ 16

typedef _Float16 half8 __attribute__((ext_vector_type(8)));
typedef float f32x4 __attribute__((ext_vector_type(4)));

__device__ __forceinline__ unsigned short f2h(float f) {
  _Float16 h = (_Float16)f;
  return *(unsigned short*)&h;
}
__device__ __forceinline__ float h2f(unsigned short u) {
  _Float16 h = *(_Float16*)&u;
  return (float)h;
}

// ---------------- precompute per-layer SSM params ----------------
__global__ void precompute_kernel(const float* __restrict__ log_dt,
                                  const float* __restrict__ logAre,
                                  const float* __restrict__ Aim,
                                  const float* __restrict__ Cre,
                                  const float* __restrict__ Cim,
                                  float* __restrict__ wbuf,
                                  float* __restrict__ c2buf,
                                  float* __restrict__ wlbuf) {
  int idx = blockIdx.x * blockDim.x + threadIdx.x;
  if (idx >= NBLK_ * D_ * N_) return;
  int blk = idx >> 14;
  int rem = idx & 16383;
  int d = rem >> 6;
  int n = rem & 63;
  float dt   = expf(log_dt[blk * D_ + d]);
  float are  = -expf(logAre[idx]);
  float aim  = Aim[idx];
  float dtar = dt * are, dtai = dt * aim;
  float er = expf(dtar);
  float wr = er * cosf(dtai);
  float wi = er * sinf(dtai);
  float inv = 1.0f / (are * are + aim * aim);
  float wm1r = wr - 1.0f;
  float br = (wm1r * are + wi * aim) * inv;
  float bi = (wi * are - wm1r * aim) * inv;
  float crv = Cre[idx], civ = Cim[idx];
  float c2r = 2.0f * (crv * br - civ * bi);
  float c2i = 2.0f * (crv * bi + civ * br);
  float eL = expf((float)LC_ * dtar);
  float angL = (float)LC_ * dtai;
  float* wb = wbuf + (size_t)((blk << 8) + d) * 128;
  wb[n] = wr; wb[64 + n] = wi;
  float* cb = c2buf + (size_t)((blk << 8) + d) * 128;
  cb[n] = c2r; cb[64 + n] = c2i;
  wlbuf[2 * idx] = eL * cosf(angL); wlbuf[2 * idx + 1] = eL * sinf(angL);
}

// ---------------- fused embedding + transpose: x -> H (fp16) and UT ----------
__global__ __launch_bounds__(256) void embed_trans(const float* __restrict__ x,
    const float* __restrict__ wemb, const float* __restrict__ bemb,
    unsigned short* __restrict__ H, unsigned short* __restrict__ UT) {
  __shared__ __align__(16) unsigned short lds[64][136];
  int bi = blockIdx.x;          // bc*4 + dq
  int bc = bi >> 2, dq = bi & 3;
  int b = bc >> 4, ch = bc & 15;
  int tid = threadIdx.x;
  int tau0 = tid >> 4;
  int dl = (tid & 15) << 2;
  float w4[4], b4[4];
#pragma unroll
  for (int i = 0; i < 4; ++i) {
    w4[i] = wemb[dq * 64 + dl + i];
    b4[i] = bemb[dq * 64 + dl + i];
  }
  for (int tt = 0; tt < 128; tt += 16) {
    int l = ch * 128 + tt + tau0;
    float xv = x[b * L_ + l];
    ushort4 hv;
    float v0 = fmaf(xv, w4[0], b4[0]);
    float v1 = fmaf(xv, w4[1], b4[1]);
    float v2 = fmaf(xv, w4[2], b4[2]);
    float v3 = fmaf(xv, w4[3], b4[3]);
    hv.x = f2h(v0); hv.y = f2h(v1); hv.z = f2h(v2); hv.w = f2h(v3);
    lds[dl + 0][tt + tau0] = hv.x;
    lds[dl + 1][tt + tau0] = hv.y;
    lds[dl + 2][tt + tau0] = hv.z;
    lds[dl + 3][tt + tau0] = hv.w;
    *(ushort4*)(H + ((size_t)(b * L_ + l)) * D_ + dq * 64 + dl) = hv;
  }
  __syncthreads();
  int r = tid >> 2, seg = (tid & 3) << 5;
  unsigned short* dst = UT + ((size_t)((dq * 64 + r) * 256 + bc)) * 128 + seg;
  const unsigned short* srow = &lds[r][seg];
  *(uint4*)(dst + 0)  = *(const uint4*)(srow + 0);
  *(uint4*)(dst + 8)  = *(const uint4*)(srow + 8);
  *(uint4*)(dst + 16) = *(const uint4*)(srow + 16);
  *(uint4*)(dst + 24) = *(const uint4*)(srow + 24);
}

// ---------------- fully-fused scan, 512 threads, register-resident A ---------
__global__ __launch_bounds__(512) void scan_fused(
    const unsigned short* __restrict__ UT,
    const float* __restrict__ WB, const float* __restrict__ C2B,
    const float* __restrict__ WLB,
    const float* __restrict__ gamma_, const float* __restrict__ beta_,
    const float* __restrict__ dskip,
    unsigned short* __restrict__ GT, int blk) {
  __shared__ __align__(16) unsigned short SLl[256 * 136];   // 69632 B
  __shared__ __align__(16) unsigned short Bm1[128 * 136];   // 34816 B (Fn -> Tn)
  __shared__ __align__(16) unsigned short Bm2[128 * 136];   // 34816 B (En)
  __shared__ float wc[256];
  __shared__ float Kt[128];
  __shared__ float Pb[128];
  __shared__ float Sb[128];
  int d = blockIdx.x;
  int tid = threadIdx.x, lane = tid & 63, w = tid >> 6;   // w: 0..7
  int wm = (w & 3) << 6;
  int wn = (w >> 2) << 6;
  int cn = lane & 15, rq = lane >> 4;
  int ko = rq << 3;
  const unsigned short* Au = UT + (size_t)d * 256 * 128;

  half8 afr[4][4];
#pragma unroll
  for (int kc2 = 0; kc2 < 4; ++kc2)
#pragma unroll
    for (int mf = 0; mf < 4; ++mf)
      afr[kc2][mf] = *(const half8*)(Au + (size_t)(wm + (mf << 4) + cn) * 128 + (kc2 << 5) + ko);

  if (tid < 128) wc[tid] = WB[(size_t)((blk << 8) + d) * 128 + tid];
  else if (tid < 256) wc[tid] = C2B[(size_t)((blk << 8) + d) * 128 + (tid - 128)];
  __syncthreads();
  int n = tid & 63;
  float gd = gamma_[blk * D_ + d], bd = beta_[blk * D_ + d], dsk = dskip[blk * D_ + d];
  {
    float wr = wc[n], wi = wc[64 + n];
    float c2r = wc[128 + n], c2i = wc[192 + n];
    int j0 = w << 4;
    float pr = 1.f, pi = 0.f, br = wr, bi = wi;
    int e = j0;
    while (e) {
      if (e & 1) { float tt = pr * br - pi * bi; pi = pr * bi + pi * br; pr = tt; }
      float t2 = br * br - bi * bi; bi = 2.f * br * bi; br = t2;
      e >>= 1;
    }
    for (int k2 = 0; k2 < 16; ++k2) {
      int j = j0 + k2;
      Bm1[n * 136 + (127 - j)]        = f2h(gd * pr);
      Bm1[(64 + n) * 136 + (127 - j)] = f2h(-gd * pi);
      float qr = pr * wr - pi * wi, qi = pr * wi + pi * wr;
      Bm2[j * 136 + n]      = f2h(c2r * qr - c2i * qi);
      Bm2[j * 136 + 64 + n] = f2h(c2r * qi + c2i * qr);
      float kc = c2r * pr - c2i * pi;
#pragma unroll
      for (int off = 1; off < 64; off <<= 1) kc += __shfl_xor(kc, off);
      if (n == 0) Kt[j] = kc + (j == 0 ? dsk : 0.f);
      pr = qr; pi = qi;
    }
  }
  if (tid < 64) {
    const float* wlp = WLB + (((size_t)((blk << 8) + d)) * 64 + tid) * 2;
    float wlr = wlp[0], wli = wlp[1];
    float nr = wlr - 1.f, ni = wli;
    float dr2 = wc[tid] - 1.f, di = wc[64 + tid];
    float iv = 1.f / (dr2 * dr2 + di * di);
    Sb[tid]      = bd * ((nr * dr2 + ni * di) * iv);
    Sb[64 + tid] = bd * (-((ni * dr2 - nr * di) * iv));
  }
  __syncthreads();   // b1

  // phase 1: SL = UT @ Fn^T + Sb
  {
    f32x4 acc[4][4];
#pragma unroll
    for (int a = 0; a < 4; ++a)
#pragma unroll
      for (int b2 = 0; b2 < 4; ++b2) acc[a][b2] = (f32x4){0.f, 0.f, 0.f, 0.f};
#pragma unroll
    for (int kc = 0; kc < 4; ++kc) {
      half8 bf4[4];
#pragma unroll
      for (int nf = 0; nf < 4; ++nf)
        bf4[nf] = *(const half8*)((const _Float16*)Bm1 + (wn + (nf << 4) + cn) * 136 + (kc << 5) + ko);
#pragma unroll
      for (int mf = 0; mf < 4; ++mf)
#pragma unroll
        for (int nf = 0; nf < 4; ++nf)
          acc[mf][nf] = __builtin_amdgcn_mfma_f32_16x16x32_f16(afr[kc][mf], bf4[nf], acc[mf][nf], 0, 0, 0);
    }
#pragma unroll
    for (int nf = 0; nf < 4; ++nf) {
      int nl = wn + (nf << 4) + cn;
      float sb = Sb[nl];
#pragma unroll
      for (int mf = 0; mf < 4; ++mf)
#pragma unroll
        for (int rr = 0; rr < 4; ++rr) {
          int row = wm + (mf << 4) + (rq << 2) + rr;
          SLl[row * 136 + nl] = f2h(acc[mf][nf][rr] + sb);
        }
    }
  }
  __syncthreads();   // b2

  if (tid < 128) {
    float ps = 0.f;
    for (int t2 = 0; t2 <= tid; ++t2) ps += Kt[t2];
    Pb[tid] = bd * ps;
  }
  // phase 2: exclusive chunk-state combine (pipelined)
  for (int task = tid; task < 1024; task += 512) {
    int b = task >> 6, nn = task & 63;
    const float* wlp = WLB + (((size_t)((blk << 8) + d)) * 64 + nn) * 2;
    float wlr = wlp[0], wli = wlp[1];
    float Sr = 0.f, Sj = 0.f;
    int row0 = b << 4;
    float tr2 = h2f(SLl[row0 * 136 + nn]);
    float tj2 = h2f(SLl[row0 * 136 + 64 + nn]);
    for (int c = 0; c < NC_; ++c) {
      int row = row0 + c;
      float ntr = 0.f, ntj = 0.f;
      if (c < NC_ - 1) {
        ntr = h2f(SLl[(row + 1) * 136 + nn]);
        ntj = h2f(SLl[(row + 1) * 136 + 64 + nn]);
      }
      SLl[row * 136 + nn]      = f2h(Sr);
      SLl[row * 136 + 64 + nn] = f2h(Sj);
      float nSr = fmaf(wlr, Sr, fmaf(wli, Sj, tr2));
      Sj = fmaf(-wli, Sr, fmaf(wlr, Sj, tj2));
      Sr = nSr;
      tr2 = ntr; tj2 = ntj;
    }
  }
  __syncthreads();   // b3

  // Tn generation into Bm1
  {
    int chunk = tid & 15, rg = tid >> 4;
#pragma unroll
    for (int it = 0; it < 4; ++it) {
      int trow = (it << 5) + rg;
      int tau0 = chunk << 3;
      unsigned short v[8];
#pragma unroll
      for (int i = 0; i < 8; ++i) {
        int tau = tau0 + i;
        v[i] = (tau <= trow) ? f2h(gd * Kt[trow - tau]) : (unsigned short)0;
      }
      *(uint4*)(Bm1 + (size_t)trow * 136 + tau0) = *(uint4*)v;
    }
  }
  __syncthreads();   // b4

  // phase 3: GT = gelu(UT@Tn^T + SL@En^T + Pb)
  {
    f32x4 acc[4][4];
#pragma unroll
    for (int a = 0; a < 4; ++a)
#pragma unroll
      for (int b2 = 0; b2 < 4; ++b2) acc[a][b2] = (f32x4){0.f, 0.f, 0.f, 0.f};
#pragma unroll
    for (int kb = 0; kb < 8; ++kb) {
      int kc = (kb & 3) << 5;
      half8 af[4], bf4[4];
      if (kb < 4) {
#pragma unroll
        for (int mf = 0; mf < 4; ++mf) af[mf] = afr[kb][mf];
#pragma unroll
        for (int nf = 0; nf < 4; ++nf)
          bf4[nf] = *(const half8*)((const _Float16*)Bm1 + (wn + (nf << 4) + cn) * 136 + kc + ko);
      } else {
#pragma unroll
        for (int mf = 0; mf < 4; ++mf)
          af[mf] = *(const half8*)((const _Float16*)SLl + (wm + (mf << 4) + cn) * 136 + kc + ko);
#pragma unroll
        for (int nf = 0; nf < 4; ++nf)
          bf4[nf] = *(const half8*)((const _Float16*)Bm2 + (wn + (nf << 4) + cn) * 136 + kc + ko);
      }
#pragma unroll
      for (int mf = 0; mf < 4; ++mf)
#pragma unroll
        for (int nf = 0; nf < 4; ++nf)
          acc[mf][nf] = __builtin_amdgcn_mfma_f32_16x16x32_f16(af[mf], bf4[nf], acc[mf][nf], 0, 0, 0);
    }
    __syncthreads();   // b5
    unsigned short* epi = SLl;
#pragma unroll
    for (int nf = 0; nf < 4; ++nf) {
      int nl = wn + (nf << 4) + cn;
      float pb2 = Pb[nl];
#pragma unroll
      for (int mf = 0; mf < 4; ++mf)
#pragma unroll
        for (int rr = 0; rr < 4; ++rr) {
          int ml = wm + (mf << 4) + (rq << 2) + rr;
          float xx = acc[mf][nf][rr] + pb2;
          float x3 = xx * xx * xx;
          float inner = 0.7978845608028654f * fmaf(0.044715f, x3, xx);
          float e = __expf(-2.f * fabsf(inner));
          float th = (1.f - e) / (1.f + e);
          th = copysignf(th, inner);
          epi[ml * 136 + nl] = f2h(0.5f * xx * (1.f + th));
        }
    }
    __syncthreads();   // b6
    int mr = tid >> 1, hf = (tid & 1) << 6;
    size_t gb = ((size_t)d * 256 + mr) * 128 + hf;
#pragma unroll
    for (int k = 0; k < 8; ++k)
      *(uint4*)(GT + gb + k * 8) = *(const uint4*)&epi[mr * 136 + hf + k * 8];
  }
}

// ---------------- W prep: WT[w][n][k] = fp16(W_w[k][n]) ----------------------
__global__ void wprep_kernel(const float* __restrict__ Wout, const float* __restrict__ fW1,
                             const float* __restrict__ fW2, unsigned short* __restrict__ WT) {
  __shared__ float tile[64][65];
  int wv = blockIdx.x >> 4;
  int tk = (blockIdx.x >> 2) & 3;
  int tn = blockIdx.x & 3;
  const float* src = (wv < 6) ? (Wout + (size_t)wv * 65536) : (wv == 6 ? fW1 : fW2);
  int r = threadIdx.x >> 4;
  int c = (threadIdx.x & 15) << 2;
  for (int rr = 0; rr < 64; rr += 16) {
    float4 v = *(const float4*)(src + (size_t)(tk * 64 + r + rr) * 256 + tn * 64 + c);
    tile[r + rr][c] = v.x; tile[r + rr][c + 1] = v.y;
    tile[r + rr][c + 2] = v.z; tile[r + rr][c + 3] = v.w;
  }
  __syncthreads();
  for (int rr = 0; rr < 64; rr += 16) {
    int n = r + rr;
    ushort4 o;
    o.x = f2h(tile[c + 0][n]); o.y = f2h(tile[c + 1][n]);
    o.z = f2h(tile[c + 2][n]); o.w = f2h(tile[c + 3][n]);
    *(ushort4*)(WT + (size_t)wv * 65536 + (size_t)(tn * 64 + n) * 256 + tk * 64 + c) = o;
  }
}

// ---------------- projection GEMM, dbuf + distance-2 prefetch ----------------
// hout = GT^T@W + bias + res; ut_next = hout^T. res staged through LDS.
__global__ __launch_bounds__(256, 2) void gemm_gt(const unsigned short* __restrict__ GT,
    const unsigned short* __restrict__ Wt, const float* __restrict__ bias,
    const unsigned short* __restrict__ res, unsigned short* __restrict__ hout,
    unsigned short* __restrict__ ut_next) {
  __shared__ __align__(16) unsigned short smem[36864];  // As[2]9216 | Bs[2]9216
  int tid = threadIdx.x;
  int bid = blockIdx.x;
  int bc = bid & 255;
  int m0 = bc * 128, n0 = (bid >> 8) << 7;
  int lane = tid & 63, w = tid >> 6;
  int wm = (w & 1) << 6, wn = (w >> 1) << 6;
  int rb = tid >> 3, cb = (tid & 7) << 3;
  int dr = tid >> 2, sg = (tid & 3) << 5;
  f32x4 acc[4][4];
#pragma unroll
  for (int mf = 0; mf < 4; ++mf)
#pragma unroll
    for (int nf = 0; nf < 4; ++nf) acc[mf][nf] = (f32x4){0.f, 0.f, 0.f, 0.f};

  uint4 gva[2][4], bva[2][4];
#pragma unroll
  for (int s = 0; s < 2; ++s) {
    int k0 = s << 6;
    const uint4* grow = (const uint4*)(GT + ((size_t)((k0 + dr) * 256 + bc)) * 128 + sg);
    gva[s][0] = grow[0]; gva[s][1] = grow[1]; gva[s][2] = grow[2]; gva[s][3] = grow[3];
#pragma unroll
    for (int rr = 0; rr < 4; ++rr)
      bva[s][rr] = *(const uint4*)(Wt + (size_t)(n0 + rb + rr * 32) * 256 + k0 + cb);
  }
  for (int kb = 0; kb < 4; ++kb) {
    int cur = kb & 1;
    unsigned short* As = smem + cur * 9216;
    unsigned short* Bs = smem + 18432 + cur * 9216;
    const unsigned short* pv = (const unsigned short*)gva[cur];
#pragma unroll
    for (int i = 0; i < 32; ++i) As[(sg + i) * 72 + dr] = pv[i];
#pragma unroll
    for (int rr = 0; rr < 4; ++rr) *(uint4*)&Bs[(rb + rr * 32) * 72 + cb] = bva[cur][rr];
    __syncthreads();
    if (kb < 2) {
      int k0 = (kb + 2) << 6;
      const uint4* grow = (const uint4*)(GT + ((size_t)((k0 + dr) * 256 + bc)) * 128 + sg);
      gva[cur][0] = grow[0]; gva[cur][1] = grow[1]; gva[cur][2] = grow[2]; gva[cur][3] = grow[3];
#pragma unroll
      for (int rr = 0; rr < 4; ++rr)
        bva[cur][rr] = *(const uint4*)(Wt + (size_t)(n0 + rb + rr * 32) * 256 + k0 + cb);
    }
#pragma unroll
    for (int kw = 0; kw < 2; ++kw) {
      int ko = (kw << 5) + ((lane >> 4) << 3);
      half8 af[4], bfr[4];
#pragma unroll
      for (int mf = 0; mf < 4; ++mf)
        af[mf] = *(const half8*)&As[(wm + (mf << 4) + (lane & 15)) * 72 + ko];
#pragma unroll
      for (int nf = 0; nf < 4; ++nf)
        bfr[nf] = *(const half8*)&Bs[(wn + (nf << 4) + (lane & 15)) * 72 + ko];
#pragma unroll
      for (int mf = 0; mf < 4; ++mf)
#pragma unroll
        for (int nf = 0; nf < 4; ++nf)
          acc[mf][nf] = __builtin_amdgcn_mfma_f32_16x16x32_f16(af[mf], bfr[nf], acc[mf][nf], 0, 0, 0);
    }
  }
  int cn = lane & 15, rq = lane >> 4;
  __syncthreads();   // all MFMA LDS reads done; smem reusable
  unsigned short* epi  = smem;           // [128][136] = 17408
  unsigned short* resL = smem + 18432;   // [128][136]
  {
    int mr = tid >> 1, hf = (tid & 1) << 6;
    const unsigned short* rsrc = res + (size_t)(m0 + mr) * 256 + n0 + hf;
#pragma unroll
    for (int k = 0; k < 8; ++k)
      *(uint4*)&resL[mr * 136 + hf + k * 8] = *(const uint4*)(rsrc + k * 8);
  }
  __syncthreads();
#pragma unroll
  for (int nf = 0; nf < 4; ++nf) {
    int nl = wn + (nf << 4) + cn;
    float bv2 = bias[n0 + nl];
#pragma unroll
    for (int mf = 0; mf < 4; ++mf)
#pragma unroll
      for (int r = 0; r < 4; ++r) {
        int ml = wm + (mf << 4) + (rq << 2) + r;
        float v = acc[mf][nf][r] + bv2 + h2f(resL[ml * 136 + nl]);
        epi[ml * 136 + nl] = f2h(v);
      }
  }
  __syncthreads();
  {
    int mr = tid >> 1, hf = (tid & 1) << 6;
    unsigned short* dst = hout + (size_t)(m0 + mr) * 256 + n0 + hf;
    const unsigned short* srow = epi + mr * 136 + hf;
#pragma unroll
    for (int k = 0; k < 8; ++k) *(uint4*)(dst + k * 8) = *(const uint4*)(srow + k * 8);
  }
  if (ut_next) {
    int nl = tid >> 1, h2 = (tid & 1) << 6;
    unsigned short* dst = ut_next + ((size_t)(n0 + nl) * 256 + bc) * 128 + h2;
#pragma unroll
    for (int k = 0; k < 8; ++k) {
      unsigned short v8[8];
#pragma unroll
      for (int e = 0; e < 8; ++e) v8[e] = epi[(h2 + k * 8 + e) * 136 + nl];
      *(uint4*)(dst + k * 8) = *(uint4*)v8;
    }
  }
}

// ---------------- FFN GEMM, dbuf + distance-2 prefetch -----------------------
__global__ __launch_bounds__(256, 2) void gemm_ffn(const unsigned short* __restrict__ A,
    const unsigned short* __restrict__ Wt, const float* __restrict__ bias,
    const unsigned short* __restrict__ res, unsigned short* __restrict__ outp) {
  __shared__ __align__(16) unsigned short smem[36864];
  int tid = threadIdx.x;
  int bid = blockIdx.x;
  int m0 = (bid & 255) << 7, n0 = (bid >> 8) << 7;
  int lane = tid & 63, w = tid >> 6;
  int wm = (w & 1) << 6, wn = (w >> 1) << 6;
  int r0 = tid >> 3;
  int c0 = (tid & 7) << 3;
  f32x4 acc[4][4];
#pragma unroll
  for (int mf = 0; mf < 4; ++mf)
#pragma unroll
    for (int nf = 0; nf < 4; ++nf) acc[mf][nf] = (f32x4){0.f, 0.f, 0.f, 0.f};

  uint4 ava[2][4], bva[2][4];
#pragma unroll
  for (int s = 0; s < 2; ++s) {
    int k0 = s << 6;
#pragma unroll
    for (int rr = 0; rr < 4; ++rr) {
      int r = r0 + rr * 32;
      ava[s][rr] = *(const uint4*)(A + (size_t)(m0 + r) * 256 + k0 + c0);
      bva[s][rr] = *(const uint4*)(Wt + (size_t)(n0 + r) * 256 + k0 + c0);
    }
  }
  for (int kb = 0; kb < 4; ++kb) {
    int cur = kb & 1;
    unsigned short* As = smem + cur * 9216;
    unsigned short* Bs = smem + 18432 + cur * 9216;
#pragma unroll
    for (int rr = 0; rr < 4; ++rr) {
      int r = r0 + rr * 32;
      *(uint4*)&As[r * 72 + c0] = ava[cur][rr];
      *(uint4*)&Bs[r * 72 + c0] = bva[cur][rr];
    }
    __syncthreads();
    if (kb < 2) {
      int k0 = (kb + 2) << 6;
#pragma unroll
      for (int rr = 0; rr < 4; ++rr) {
        int r = r0 + rr * 32;
        ava[cur][rr] = *(const uint4*)(A + (size_t)(m0 + r) * 256 + k0 + c0);
        bva[cur][rr] = *(const uint4*)(Wt + (size_t)(n0 + r) * 256 + k0 + c0);
      }
    }
#pragma unroll
    for (int kw = 0; kw < 2; ++kw) {
      int ko = (kw << 5) + ((lane >> 4) << 3);
      half8 af[4], bfr[4];
#pragma unroll
      for (int mf = 0; mf < 4; ++mf)
        af[mf] = *(const half8*)&As[(wm + (mf << 4) + (lane & 15)) * 72 + ko];
#pragma unroll
      for (int nf = 0; nf < 4; ++nf)
        bfr[nf] = *(const half8*)&Bs[(wn + (nf << 4) + (lane & 15)) * 72 + ko];
#pragma unroll
      for (int mf = 0; mf < 4; ++mf)
#pragma unroll
        for (int nf = 0; nf < 4; ++nf)
          acc[mf][nf] = __builtin_amdgcn_mfma_f32_16x16x32_f16(af[mf], bfr[nf], acc[mf][nf], 0, 0, 0);
    }
  }
  int cn = lane & 15, rq = lane >> 4;
  __syncthreads();
  unsigned short* epi = smem;
#pragma unroll
  for (int nf = 0; nf < 4; ++nf) {
    int nl = wn + (nf << 4) + cn;
#pragma unroll
    for (int r = 0; r < 4; ++r) {
#pragma unroll
      for (int mf = 0; mf < 4; ++mf) {
        int ml = wm + (mf << 4) + (rq << 2) + r;
        epi[ml * 136 + nl] = f2h(acc[mf][nf][r]);
      }
    }
  }
  __syncthreads();
  int mr = tid >> 1, hf = (tid & 1) << 6;
  unsigned short* dst = outp + (size_t)(m0 + mr) * 256 + n0 + hf;
#pragma unroll
  for (int k = 0; k < 8; ++k) {
    uint4 c = *(const uint4*)&epi[mr * 136 + hf + k * 8];
    uint4 rv = (uint4){0, 0, 0, 0};
    if (res) rv = *(const uint4*)(res + (size_t)(m0 + mr) * 256 + n0 + hf + k * 8);
    const unsigned short* cp = (const unsigned short*)&c;
    const unsigned short* rp = (const unsigned short*)&rv;
    unsigned short o8[8];
#pragma unroll
    for (int e = 0; e < 8; ++e) {
      float v = h2f(cp[e]) + bias[n0 + hf + k * 8 + e];
      if (res) v += h2f(rp[e]);
      o8[e] = f2h(fmaxf(v, 0.f));
    }
    *(uint4*)(dst + k * 8) = *(uint4*)o8;
  }
}

// ---------------- head ------------------------
__global__ void head1_kernel(const unsigned short* __restrict__ H, float* __restrict__ part) {
  int b = blockIdx.x, ls = blockIdx.y, d = threadIdx.x;
  const unsigned short* p = H + ((size_t)(b * L_ + ls * 128)) * D_ + d;
  float sum = 0.f;
  for (int l = 0; l < 128; ++l) sum += h2f(p[(size_t)l * D_]);
  part[(b * 16 + ls) * D_ + d] = sum;
}

__global__ void head2_kernel(const float* __restrict__ part, const float* __restrict__ fcW,
                             const float* __restrict__ fcb, float* __restrict__ out) {
  int b = blockIdx.x, d = threadIdx.x;
  float sum = 0.f;
  for (int i = 0; i < 16; ++i) sum += part[(b * 16 + i) * D_ + d];
  __shared__ float meanv[D_];
  meanv[d] = sum * (1.0f / (float)L_);
  __syncthreads();
  if (d < 2) {
    float accv = fcb[d];
    for (int k = 0; k < D_; ++k) accv = fmaf(meanv[k], fcW[k * 2 + d], accv);
    out[b * 2 + d] = accv;
  }
}

extern "C" void kernel_launch(void* const* d_in, const int* in_sizes, int n_in,
                              void* d_out, int out_size, void* d_ws, size_t ws_size,
                              hipStream_t stream) {
  const float* x      = (const float*)d_in[0];
  const float* W_emb  = (const float*)d_in[1];
  const float* b_emb  = (const float*)d_in[2];
  const float* log_dt = (const float*)d_in[3];
  const float* logAre = (const float*)d_in[4];
  const float* Aim    = (const float*)d_in[5];
  const float* Cre    = (const float*)d_in[6];
  const float* Cim    = (const float*)d_in[7];
  const float* Dskip  = (const float*)d_in[8];
  const float* Wout   = (const float*)d_in[9];
  const float* bout   = (const float*)d_in[10];
  const float* gamma_ = (const float*)d_in[11];
  const float* beta_  = (const float*)d_in[12];
  const float* fW1    = (const float*)d_in[13];
  const float* fb1    = (const float*)d_in[14];
  const float* fW2    = (const float*)d_in[15];
  const float* fb2    = (const float*)d_in[16];
  const float* fcW    = (const float*)d_in[17];
  const float* fcb    = (const float*)d_in[18];
  float* outp = (float*)d_out;

  const size_t HSZ = (size_t)B_ * L_ * D_;   // 8388608
  float* WB     = (float*)d_ws;
  float* C2B    = WB + (size_t)NBLK_ * D_ * 128;
  float* WLB    = C2B + (size_t)NBLK_ * D_ * 128;
  unsigned short* H   = (unsigned short*)(WLB + (size_t)NBLK_ * D_ * N_ * 2);
  unsigned short* R   = H + HSZ;
  unsigned short* UT  = R + HSZ;
  unsigned short* GT  = UT + HSZ;
  unsigned short* Gbf = GT;
  unsigned short* WT  = GT + HSZ;

  precompute_kernel<<<(NBLK_ * D_ * N_ + 255) / 256, 256, 0, stream>>>(
      log_dt, logAre, Aim, Cre, Cim, WB, C2B, WLB);
  wprep_kernel<<<128, 256, 0, stream>>>(Wout, fW1, fW2, WT);
  embed_trans<<<1024, 256, 0, stream>>>(x, W_emb, b_emb, H, UT);

  const unsigned short* hin_t[6]  = {H, H, H, H, R, H};
  unsigned short*       hout_t[6] = {H, H, H, R, H, H};
  for (int i = 0; i < 6; ++i) {
    scan_fused<<<256, 512, 0, stream>>>(UT, WB, C2B, WLB, gamma_, beta_, Dskip, GT, i);
    gemm_gt<<<512, 256, 0, stream>>>(
        GT, WT + (size_t)i * 65536, bout + i * D_, hin_t[i], hout_t[i],
        (i < 5) ? UT : nullptr);
  }
  // feedforward of the FS4Ddeq block + skip from R
  gemm_ffn<<<512, 256, 0, stream>>>(H, WT + (size_t)6 * 65536, fb1, nullptr, Gbf);
  gemm_ffn<<<512, 256, 0, stream>>>(Gbf, WT + (size_t)7 * 65536, fb2, R, H);
  head1_kernel<<<dim3(16, 16), 256, 0, stream>>>(H, WB);
  head2_kernel<<<16, 256, 0, stream>>>(WB, fcW, fcb, outp);
}